// Round 1
// baseline (13017.325 us; speedup 1.0000x reference)
//
#include <hip/hip_runtime.h>
#include <math.h>

#define VV 32000
#define EE 512
#define HH 512
#define BB 16
#define TT 128
#define SS 128
#define XD 1024      // E + H
#define NPB 500      // projection blocks
#define VB 64        // vocab rows per projection block
#define SROW 1728    // LDS row stride for lstm xs (1536 + stagger headroom)

__device__ __forceinline__ float sigf(float x) { return 1.0f / (1.0f + expf(-x)); }

// ---------------------------------------------------------------------------
// k_proj: blocks [0,npb): logits[t] = h1 @ out_w^T + out_b  (+ per-block
//         softmax/argmax partials).  blocks [npb, npb+16): scores for next
//         step: scores[b,s] = dot(h1[b], enc[s,b,:]).
// ---------------------------------------------------------------------------
__global__ __launch_bounds__(256) void k_proj(
    const float* __restrict__ out_w, const float* __restrict__ out_b,
    const float* __restrict__ h1,        // [B][H] (new h1)
    const float* __restrict__ enc,       // [S][B][H]
    float* __restrict__ raw, long rawstride, int nt_raw,
    float* __restrict__ scores,          // [B][S]
    float* __restrict__ pmax, float* __restrict__ psum, int* __restrict__ pidx,
    int npb, int do_scores)
{
    const int blk = blockIdx.x;
    const int tid = threadIdx.x;

    if (blk >= npb) {
        if (!do_scores) return;
        const int b = blk - npb;
        const int s = tid >> 1, h = tid & 1;
        const float* er = enc + ((long)s * BB + b) * HH + h * 256;
        const float* hh = h1 + b * HH + h * 256;
        float acc = 0.f;
        #pragma unroll 8
        for (int k = 0; k < 256; k += 4) {
            float4 w = *(const float4*)(er + k);
            float4 x = *(const float4*)(hh + k);
            acc += w.x * x.x + w.y * x.y + w.z * x.z + w.w * x.w;
        }
        acc += __shfl_xor(acc, 1);
        if (h == 0) scores[b * SS + s] = acc;
        return;
    }

    __shared__ float h1t[10304];      // staggered [k][b] layout
    __shared__ float lv[64][17];      // logits tile for partial reduce

    for (int i = tid; i < BB * HH; i += 256) {
        int b = i >> 9, k = i & 511;
        h1t[k * 20 + ((k >> 6) << 2) + b] = h1[i];
    }
    __syncthreads();

    const int q = tid >> 3;           // 0..31 -> owns rows v, v+1
    const int h = tid & 7;            // k-range eighth
    const int v = blk * VB + q * 2;
    const float* w0 = out_w + (long)v * HH;
    const float* w1 = w0 + HH;
    float acc0[16], acc1[16];
    #pragma unroll
    for (int i = 0; i < 16; ++i) { acc0[i] = 0.f; acc1[i] = 0.f; }

    const int kbase = h * 64;
    for (int kk = 0; kk < 64; kk += 4) {
        const int k = kbase + kk;
        float a0f[4], a1f[4];
        *(float4*)a0f = *(const float4*)(w0 + k);
        *(float4*)a1f = *(const float4*)(w1 + k);
        #pragma unroll
        for (int d = 0; d < 4; ++d) {
            const int kd = k + d;
            const float* hp = &h1t[kd * 20 + ((kd >> 6) << 2)];
            const float wA = a0f[d], wB = a1f[d];
            #pragma unroll
            for (int g = 0; g < 4; ++g) {
                float hvf[4];
                *(float4*)hvf = *(const float4*)(hp + g * 4);
                acc0[g*4+0] += wA * hvf[0]; acc0[g*4+1] += wA * hvf[1];
                acc0[g*4+2] += wA * hvf[2]; acc0[g*4+3] += wA * hvf[3];
                acc1[g*4+0] += wB * hvf[0]; acc1[g*4+1] += wB * hvf[1];
                acc1[g*4+2] += wB * hvf[2]; acc1[g*4+3] += wB * hvf[3];
            }
        }
    }
    #pragma unroll
    for (int i = 0; i < 16; ++i) {
        float a = acc0[i];
        a += __shfl_xor(a, 1); a += __shfl_xor(a, 2); a += __shfl_xor(a, 4);
        acc0[i] = a;
        float c = acc1[i];
        c += __shfl_xor(c, 1); c += __shfl_xor(c, 2); c += __shfl_xor(c, 4);
        acc1[i] = c;
    }
    if (h == 0) {
        const float b0 = out_b[v], b1 = out_b[v + 1];
        #pragma unroll
        for (int b = 0; b < 16; ++b) {
            const float l0 = acc0[b] + b0, l1 = acc1[b] + b1;
            lv[q * 2][b] = l0; lv[q * 2 + 1][b] = l1;
            float* dst = raw + (long)b * rawstride + v;
            if (nt_raw) {
                __builtin_nontemporal_store(l0, dst);
                __builtin_nontemporal_store(l1, dst + 1);
            } else {
                dst[0] = l0; dst[1] = l1;
            }
        }
    }
    __syncthreads();

    // per-b block partials: max / first-argmax / sum(exp(x - max))
    const int b2 = tid >> 4;
    const int l  = tid & 15;
    float vals[4];
    float m = -INFINITY; int mi = 0;
    #pragma unroll
    for (int r = 0; r < 4; ++r) {
        const float x = lv[l * 4 + r][b2];
        vals[r] = x;
        if (x > m) { m = x; mi = l * 4 + r; }
    }
    #pragma unroll
    for (int off = 8; off >= 1; off >>= 1) {
        const float om = __shfl_xor(m, off);
        const int   oi = __shfl_xor(mi, off);
        if (om > m || (om == m && oi < mi)) { m = om; mi = oi; }
    }
    float z = 0.f;
    #pragma unroll
    for (int r = 0; r < 4; ++r) z += expf(vals[r] - m);
    #pragma unroll
    for (int off = 8; off >= 1; off >>= 1) z += __shfl_xor(z, off);
    if (l == 0) {
        pmax[blk * 16 + b2] = m;
        psum[blk * 16 + b2] = z;
        pidx[blk * 16 + b2] = blk * VB + mi;
    }
}

// ---------------------------------------------------------------------------
// k_prep: per step t.  256 blocks: b = blk>>4, chunk = blk&15.
//   mode&1 (t>=1): combine partials -> tok, lse; write logp[t-1], seq[t-1]
//   mode&2 (t<T):  softmax(scores) -> aw; write attn[t]; build x=[emb|ctx]
// ---------------------------------------------------------------------------
__global__ __launch_bounds__(256) void k_prep(
    const float* __restrict__ embedding,
    const float* __restrict__ enc,
    const float* __restrict__ scores,
    const float* __restrict__ raw, long rawstride, int nt_raw,
    const float* __restrict__ pmax, const float* __restrict__ psum, const int* __restrict__ pidx,
    float* __restrict__ xout,
    float* __restrict__ logp_out, float* __restrict__ seq_out, float* __restrict__ attn_out,
    int t, int mode, int npb)
{
    const int b = blockIdx.x >> 4;
    const int chunk = blockIdx.x & 15;
    const int tid = threadIdx.x;

    __shared__ float sm[256]; __shared__ int si[256]; __shared__ float ssum[256];
    __shared__ float aw[SS];  __shared__ float sred[2];

    int tok = 1;
    if (mode & 1) {
        float m = -INFINITY; int mi = 0x7fffffff;
        for (int i = tid; i < npb; i += 256) {
            const float pm = pmax[i * 16 + b];
            const int   pi = pidx[i * 16 + b];
            if (pm > m || (pm == m && pi < mi)) { m = pm; mi = pi; }
        }
        sm[tid] = m; si[tid] = mi;
        __syncthreads();
        for (int o = 128; o > 0; o >>= 1) {
            if (tid < o) {
                const float om = sm[tid + o]; const int oi = si[tid + o];
                if (om > sm[tid] || (om == sm[tid] && oi < si[tid])) { sm[tid] = om; si[tid] = oi; }
            }
            __syncthreads();
        }
        const float M = sm[0]; tok = si[0];
        float z = 0.f;
        for (int i = tid; i < npb; i += 256)
            z += psum[i * 16 + b] * expf(pmax[i * 16 + b] - M);
        ssum[tid] = z;
        __syncthreads();
        for (int o = 128; o > 0; o >>= 1) {
            if (tid < o) ssum[tid] += ssum[tid + o];
            __syncthreads();
        }
        const float lse = M + logf(ssum[0]);

        const float* rb = raw + (long)b * rawstride + chunk * 2000;
        float* ob = logp_out + ((long)b * TT + (t - 1)) * VV + chunk * 2000;
        if (nt_raw) {
            for (int i = tid; i < 2000; i += 256)
                __builtin_nontemporal_store(__builtin_nontemporal_load(rb + i) - lse, ob + i);
        } else {
            for (int i = tid; i < 2000; i += 256)
                __builtin_nontemporal_store(rb[i] - lse, ob + i);
        }
        if (chunk == 0 && tid == 0)
            __builtin_nontemporal_store((float)tok, seq_out + b * TT + (t - 1));
    }
    if (!(mode & 2)) return;
    __syncthreads();

    // softmax over scores[b][0..S)
    if (tid == 0) {
        float mm = -INFINITY;
        for (int s = 0; s < SS; ++s) mm = fmaxf(mm, scores[b * SS + s]);
        sred[0] = mm;
    }
    __syncthreads();
    if (tid < SS) aw[tid] = expf(scores[b * SS + tid] - sred[0]);
    __syncthreads();
    if (tid == 0) {
        float sum = 0.f;
        for (int s = 0; s < SS; ++s) sum += aw[s];
        sred[1] = 1.0f / sum;
    }
    __syncthreads();
    if (tid < SS) aw[tid] *= sred[1];
    __syncthreads();
    if (chunk == 0 && tid < SS)
        __builtin_nontemporal_store(aw[tid], attn_out + ((long)b * TT + t) * SS + tid);

    const int e0 = chunk * 64;
    if (e0 < EE) {
        for (int i = tid; i < 64; i += 256)
            xout[b * XD + e0 + i] = embedding[(long)tok * EE + e0 + i];
    } else {
        const int h0 = e0 - EE;
        __shared__ float ps[4][64];
        const int o = tid & 63, part = tid >> 6;
        float a = 0.f;
        for (int s2 = part * 32; s2 < part * 32 + 32; ++s2)
            a += aw[s2] * enc[((long)s2 * BB + b) * HH + h0 + o];
        ps[part][o] = a;
        __syncthreads();
        if (tid < 64)
            xout[b * XD + e0 + tid] = ps[0][tid] + ps[1][tid] + ps[2][tid] + ps[3][tid];
    }
}

// ---------------------------------------------------------------------------
// k_lstm: one LSTM cell.  256 blocks, block owns 2 h-indices (8 gate rows,
// all 16 batches).  Virtual input = concat(xin[b][0:xlen], hprev[b][0:H])
// staged (staggered) in LDS; 8 gate-row accumulators per thread.
// ---------------------------------------------------------------------------
__global__ __launch_bounds__(256) void k_lstm(
    const float* __restrict__ wih, const float* __restrict__ whh,
    const float* __restrict__ bih, const float* __restrict__ bhh,
    const float* __restrict__ xin, int xlen, int xshift,
    const float* __restrict__ hprev, const float* __restrict__ cprev,
    float* __restrict__ hout, float* __restrict__ cout)
{
    __shared__ float xs[BB * SROW];        // staggered [b][k] virtual input
    __shared__ float gpart[8 * 16 * 17];   // [r][b][h] partials (+slot 16 = total)

    const int tid = threadIdx.x;
    const int j0 = blockIdx.x * 2;
    const int tot = xlen + HH;

    const int xmask = xlen - 1;
    for (int i = tid; i < (BB << xshift); i += 256) {
        const int b = i >> xshift, k = i & xmask;
        xs[b * SROW + k + ((k >> 5) << 2)] = xin[i];
    }
    for (int i = tid; i < BB * HH; i += 256) {
        const int b = i >> 9, k = xlen + (i & 511);
        xs[b * SROW + k + ((k >> 5) << 2)] = hprev[i];
    }
    __syncthreads();

    const int b = tid >> 4;        // 0..15
    const int h = tid & 15;        // k-range sixteenth
    const int klen = tot >> 4;     // 96 (layer0) or 64 (layer1)
    const int k0 = h * klen;

    const float* pih[8]; const float* phh[8];
    #pragma unroll
    for (int r = 0; r < 8; ++r) {
        const int g = r >> 1, jj = r & 1;
        const int row = g * HH + j0 + jj;
        pih[r] = wih + (long)row * xlen;
        phh[r] = whh + (long)row * HH - xlen;   // so phh[r][k] == whh[row][k-xlen]
    }
    float acc[8];
    #pragma unroll
    for (int r = 0; r < 8; ++r) acc[r] = 0.f;

    const float* xb = xs + b * SROW;
    #pragma unroll 4
    for (int i = 0; i < klen; i += 4) {
        const int k = k0 + i;
        float xvf[4];
        *(float4*)xvf = *(const float4*)(xb + k + ((k >> 5) << 2));
        #pragma unroll
        for (int r = 0; r < 8; ++r) {
            const float* wp = ((k < xlen) ? pih[r] : phh[r]) + k;
            float wvf[4];
            *(float4*)wvf = *(const float4*)wp;
            acc[r] += wvf[0]*xvf[0] + wvf[1]*xvf[1] + wvf[2]*xvf[2] + wvf[3]*xvf[3];
        }
    }
    #pragma unroll
    for (int r = 0; r < 8; ++r) gpart[(r * 16 + b) * 17 + h] = acc[r];
    __syncthreads();

    if (tid < 128) {
        const int r = tid >> 4, bb = tid & 15;
        float s = 0.f;
        #pragma unroll
        for (int hh2 = 0; hh2 < 16; ++hh2) s += gpart[(r * 16 + bb) * 17 + hh2];
        const int g = r >> 1, jj = r & 1;
        const int row = g * HH + j0 + jj;
        gpart[(r * 16 + bb) * 17 + 16] = s + bih[row] + bhh[row];
    }
    __syncthreads();

    if (tid < 32) {
        const int bb = tid >> 1, jj = tid & 1;
        const float ii = gpart[((0 + jj) * 16 + bb) * 17 + 16];
        const float ff = gpart[((2 + jj) * 16 + bb) * 17 + 16];
        const float gg = gpart[((4 + jj) * 16 + bb) * 17 + 16];
        const float oo = gpart[((6 + jj) * 16 + bb) * 17 + 16];
        const int j = j0 + jj;
        const float cp = cprev[bb * HH + j];
        const float cn = sigf(ff) * cp + sigf(ii) * tanhf(gg);
        const float hn = sigf(oo) * tanhf(cn);
        hout[bb * HH + j] = hn;
        cout[bb * HH + j] = cn;
    }
}

// ---------------------------------------------------------------------------
extern "C" void kernel_launch(void* const* d_in, const int* in_sizes, int n_in,
                              void* d_out, int out_size, void* d_ws, size_t ws_size,
                              hipStream_t stream)
{
    (void)in_sizes; (void)n_in; (void)out_size;

    const float* embedding = (const float*)d_in[0];
    const float* h_in  = (const float*)d_in[1];
    const float* c_in  = (const float*)d_in[2];
    const float* enc   = (const float*)d_in[3];
    const float* w_ih0 = (const float*)d_in[4];
    const float* w_hh0 = (const float*)d_in[5];
    const float* b_ih0 = (const float*)d_in[6];
    const float* b_hh0 = (const float*)d_in[7];
    const float* w_ih1 = (const float*)d_in[8];
    const float* w_hh1 = (const float*)d_in[9];
    const float* b_ih1 = (const float*)d_in[10];
    const float* b_hh1 = (const float*)d_in[11];
    const float* out_w = (const float*)d_in[12];
    const float* out_b = (const float*)d_in[13];

    float* out = (float*)d_out;
    const long logp_sz = (long)BB * TT * VV;
    const long seq_sz  = (long)BB * TT;
    float* seq_out  = out + logp_sz;
    float* attn_out = out + logp_sz + seq_sz;

    float* ws = (float*)d_ws;
    const int BH = BB * HH;
    float* st     = ws;                      // 2 bufs x {h0,c0,h1,c1} x B*H
    float* xbuf   = st + 8 * BH;             // [B][XD]
    float* scores = xbuf + BB * XD;          // [B][S]
    float* pm     = scores + BB * SS;        // [NPB][B]
    float* psm    = pm + NPB * BB;
    int*   pid    = (int*)(psm + NPB * BB);
    float* lraw   = (float*)(pid + NPB * BB);  // [B][V]
    const size_t need = (size_t)((char*)(lraw + (long)BB * VV) - (char*)ws);
    const int usews = (ws_size >= need) ? 1 : 0;
    const int nt_raw = usews ? 0 : 1;
    const long rawstride = usews ? (long)VV : (long)TT * VV;

    auto sbuf = [&](int buf, int slot) { return st + (size_t)(buf * 4 + slot) * BH; };

    // prologue: scores for step 0 from initial h1 = h_in[1]
    k_proj<<<16, 256, 0, stream>>>(out_w, out_b, h_in + BH, enc,
                                   usews ? lraw : out, rawstride, nt_raw,
                                   scores, pm, psm, pid, 0, 1);

    for (int t = 0; t <= TT; ++t) {
        const int mode = (t > 0 ? 1 : 0) | (t < TT ? 2 : 0);
        const float* rawprev = usews ? lraw : out + (size_t)(t > 0 ? t - 1 : 0) * VV;
        k_prep<<<256, 256, 0, stream>>>(embedding, enc, scores,
                                        rawprev, rawstride, nt_raw,
                                        pm, psm, pid, xbuf,
                                        out, seq_out, attn_out, t, mode, NPB);
        if (t == TT) break;

        const float* h0c = t ? sbuf(t & 1, 0) : h_in;
        const float* c0c = t ? sbuf(t & 1, 1) : c_in;
        const float* h1c = t ? sbuf(t & 1, 2) : h_in + BH;
        const float* c1c = t ? sbuf(t & 1, 3) : c_in + BH;
        const int n = (t + 1) & 1;
        float* h0n = sbuf(n, 0); float* c0n = sbuf(n, 1);
        float* h1n = sbuf(n, 2); float* c1n = sbuf(n, 3);

        k_lstm<<<256, 256, 0, stream>>>(w_ih0, w_hh0, b_ih0, b_hh0,
                                        xbuf, 1024, 10, h0c, c0c, h0n, c0n);
        k_lstm<<<256, 256, 0, stream>>>(w_ih1, w_hh1, b_ih1, b_hh1,
                                        h0n, 512, 9, h1c, c1c, h1n, c1n);

        float* rawt = usews ? lraw : out + (size_t)t * VV;
        k_proj<<<NPB + 16, 256, 0, stream>>>(out_w, out_b, h1n, enc,
                                             rawt, rawstride, nt_raw,
                                             scores, pm, psm, pid, NPB, 1);
    }
}